// Round 7
// baseline (269.435 us; speedup 1.0000x reference)
//
#include <hip/hip_runtime.h>
#include <math.h>

#define N_NODES 100000
#define D_FEAT  128
#define N_EDGES 640000

// native vector type for nontemporal builtin (HIP_vector_type is rejected)
typedef float nfloat4 __attribute__((ext_vector_type(4)));

// ---------------------------------------------------------------------------
// Shared body: a[n] = feat[n]·W[:128] + bias, c[n] = feat[n]·W[128:].
// 32-lane groups, float4/lane, 4 nodes in flight, grid-stride.
// ---------------------------------------------------------------------------
__device__ __forceinline__ void node_dots_body(
    const float* __restrict__ feat, const float4 w0, const float4 w1,
    const float bb, float* __restrict__ a, float* __restrict__ c,
    const int lane32, const int grp, const int ngrp)
{
    for (int n0 = grp * 4; n0 < N_NODES; n0 += ngrp * 4) {
        float4 f[4];
        #pragma unroll
        for (int j = 0; j < 4; ++j) {
            f[j] = *reinterpret_cast<const float4*>(
                feat + (size_t)(n0 + j) * D_FEAT + lane32 * 4);
        }

        float pa[4], pc[4];
        #pragma unroll
        for (int j = 0; j < 4; ++j) {
            pa[j] = f[j].x * w0.x + f[j].y * w0.y + f[j].z * w0.z + f[j].w * w0.w;
            pc[j] = f[j].x * w1.x + f[j].y * w1.y + f[j].z * w1.z + f[j].w * w1.w;
        }

        #pragma unroll
        for (int off = 16; off > 0; off >>= 1) {
            #pragma unroll
            for (int j = 0; j < 4; ++j) {
                pa[j] += __shfl_down(pa[j], off, 32);
                pc[j] += __shfl_down(pc[j], off, 32);
            }
        }

        if (lane32 == 0) {
            #pragma unroll
            for (int j = 0; j < 4; ++j) {
                a[n0 + j] = pa[j] + bb;
                c[n0 + j] = pc[j];
            }
        }
    }
}

__global__ __launch_bounds__(256) void node_dots_kernel(
    const float* __restrict__ feat, const float* __restrict__ W,
    const float* __restrict__ bias,
    float* __restrict__ a, float* __restrict__ c)
{
    const int lane32 = threadIdx.x & 31;
    const int grp    = (blockIdx.x * blockDim.x + threadIdx.x) >> 5;
    const int ngrp   = (gridDim.x * blockDim.x) >> 5;
    const float4 w0 = *reinterpret_cast<const float4*>(W + lane32 * 4);
    const float4 w1 = *reinterpret_cast<const float4*>(W + D_FEAT + lane32 * 4);
    node_dots_body(feat, w0, w1, bias[0], a, c, lane32, grp, ngrp);
}

// PROBE: same body x12 reps into scratch; surfaces in rocprof top-5.
__global__ __launch_bounds__(256) void node_dots_probe(
    const float* __restrict__ feat, const float* __restrict__ W,
    const float* __restrict__ bias,
    float* __restrict__ a, float* __restrict__ c)
{
    const int lane32 = threadIdx.x & 31;
    const int grp    = (blockIdx.x * blockDim.x + threadIdx.x) >> 5;
    const int ngrp   = (gridDim.x * blockDim.x) >> 5;
    const float4 w0 = *reinterpret_cast<const float4*>(W + lane32 * 4);
    const float4 w1 = *reinterpret_cast<const float4*>(W + D_FEAT + lane32 * 4);
    const float bb = bias[0];
    for (int rr = 0; rr < 12; ++rr) {
        node_dots_body(feat, w0, w1, bb, a, c, lane32, grp, ngrp);
        asm volatile("" ::: "memory");   // forbid cross-rep CSE/merging
    }
}

// ---------------------------------------------------------------------------
// Shared body: out[e] = sigmoid(a[src] + c[dst]), 4 edges/thread, NT store.
// ---------------------------------------------------------------------------
__device__ __forceinline__ void edge_body(
    const int* __restrict__ ei, const float* __restrict__ a,
    const float* __restrict__ c, float* __restrict__ out, const int t)
{
    const int e0 = t * 4;
    if (e0 >= N_EDGES) return;

    const int4 s = *reinterpret_cast<const int4*>(ei + e0);
    const int4 d = *reinterpret_cast<const int4*>(ei + N_EDGES + e0);

    const float as0 = a[s.x], as1 = a[s.y], as2 = a[s.z], as3 = a[s.w];
    const float cd0 = c[d.x], cd1 = c[d.y], cd2 = c[d.z], cd3 = c[d.w];

    nfloat4 o;
    o.x = 1.0f / (1.0f + __expf(-(as0 + cd0)));
    o.y = 1.0f / (1.0f + __expf(-(as1 + cd1)));
    o.z = 1.0f / (1.0f + __expf(-(as2 + cd2)));
    o.w = 1.0f / (1.0f + __expf(-(as3 + cd3)));

    __builtin_nontemporal_store(o, reinterpret_cast<nfloat4*>(out + e0));
}

__global__ __launch_bounds__(256) void edge_kernel(
    const int* __restrict__ ei,
    const float* __restrict__ a, const float* __restrict__ c,
    float* __restrict__ out)
{
    const int t = blockIdx.x * blockDim.x + threadIdx.x;
    edge_body(ei, a, c, out, t);
}

// PROBE: same body x32 reps into scratch.
__global__ __launch_bounds__(256) void edge_probe(
    const int* __restrict__ ei,
    const float* __restrict__ a, const float* __restrict__ c,
    float* __restrict__ out)
{
    const int t = blockIdx.x * blockDim.x + threadIdx.x;
    for (int rr = 0; rr < 32; ++rr) {
        edge_body(ei, a, c, out, t);
        asm volatile("" ::: "memory");
    }
}

extern "C" void kernel_launch(void* const* d_in, const int* in_sizes, int n_in,
                              void* d_out, int out_size, void* d_ws, size_t ws_size,
                              hipStream_t stream)
{
    const float* feat = (const float*)d_in[0];
    const int*   ei   = (const int*)d_in[1];
    const float* W    = (const float*)d_in[2];
    const float* b    = (const float*)d_in[3];
    float*       out  = (float*)d_out;

    float* a = (float*)d_ws;
    float* c = a + N_NODES;

    const int nthreads = N_EDGES / 4;            // 160000
    const int nblk2 = (nthreads + 255) / 256;    // 625

    // ---- real path (identical to R6) ----
    node_dots_kernel<<<2048, 256, 0, stream>>>(feat, W, b, a, c);
    edge_kernel<<<nblk2, 256, 0, stream>>>(ei, a, c, out);

    // ---- instrumentation probes (scratch-only writes) ----
    const size_t probe_need = (size_t)(2 * N_NODES + 2 * N_NODES + N_EDGES) * sizeof(float);
    if (ws_size >= probe_need) {
        float* a2   = c + N_NODES;
        float* c2   = a2 + N_NODES;
        float* out2 = c2 + N_NODES;
        node_dots_probe<<<2048, 256, 0, stream>>>(feat, W, b, a2, c2);
        edge_probe<<<nblk2, 256, 0, stream>>>(ei, a2, c2, out2);
    }
}

// Round 8
// 22.571 us; speedup vs baseline: 11.9371x; 11.9371x over previous
//
#include <hip/hip_runtime.h>
#include <math.h>

#define N_NODES 100000
#define D_FEAT  128
#define N_EDGES 640000

// ---------------------------------------------------------------------------
// Kernel 1: a[n] = feat[n]·W[:128] + bias, c[n] = feat[n]·W[128:].
// 32-lane groups, float4/lane (512 B per row per group), 4 nodes in flight
// per iteration. Grid-stride. Bias folded into a[]. Steady-state this runs
// L3-warm at ~3 µs (R7 probe: 12 reps < 40 µs).
// ---------------------------------------------------------------------------
__global__ __launch_bounds__(256) void node_dots_kernel(
    const float* __restrict__ feat, const float* __restrict__ W,
    const float* __restrict__ bias,
    float* __restrict__ a, float* __restrict__ c)
{
    const int lane32 = threadIdx.x & 31;
    const int grp    = (blockIdx.x * blockDim.x + threadIdx.x) >> 5;
    const int ngrp   = (gridDim.x * blockDim.x) >> 5;

    const float4 w0 = *reinterpret_cast<const float4*>(W + lane32 * 4);
    const float4 w1 = *reinterpret_cast<const float4*>(W + D_FEAT + lane32 * 4);
    const float bb = bias[0];

    for (int n0 = grp * 4; n0 < N_NODES; n0 += ngrp * 4) {
        float4 f[4];
        #pragma unroll
        for (int j = 0; j < 4; ++j) {
            f[j] = *reinterpret_cast<const float4*>(
                feat + (size_t)(n0 + j) * D_FEAT + lane32 * 4);
        }

        float pa[4], pc[4];
        #pragma unroll
        for (int j = 0; j < 4; ++j) {
            pa[j] = f[j].x * w0.x + f[j].y * w0.y + f[j].z * w0.z + f[j].w * w0.w;
            pc[j] = f[j].x * w1.x + f[j].y * w1.y + f[j].z * w1.z + f[j].w * w1.w;
        }

        #pragma unroll
        for (int off = 16; off > 0; off >>= 1) {
            #pragma unroll
            for (int j = 0; j < 4; ++j) {
                pa[j] += __shfl_down(pa[j], off, 32);
                pc[j] += __shfl_down(pc[j], off, 32);
            }
        }

        if (lane32 == 0) {
            #pragma unroll
            for (int j = 0; j < 4; ++j) {
                a[n0 + j] = pa[j] + bb;
                c[n0 + j] = pc[j];
            }
        }
    }
}

// ---------------------------------------------------------------------------
// Kernel 2: out[e] = sigmoid(a[src] + c[dst]), ONE edge per thread.
// R7 probe showed 4-edges/thread was latency-bound at 2.4 waves/SIMD;
// 1 edge/thread gives 10000 waves (~39/CU) of gather-latency hiding.
// ---------------------------------------------------------------------------
__global__ __launch_bounds__(256) void edge_kernel(
    const int* __restrict__ ei,
    const float* __restrict__ a, const float* __restrict__ c,
    float* __restrict__ out)
{
    const int e = blockIdx.x * blockDim.x + threadIdx.x;
    if (e >= N_EDGES) return;

    const int s = ei[e];
    const int d = ei[N_EDGES + e];

    const float as = a[s];
    const float cd = c[d];

    const float o = 1.0f / (1.0f + __expf(-(as + cd)));
    __builtin_nontemporal_store(o, out + e);
}

extern "C" void kernel_launch(void* const* d_in, const int* in_sizes, int n_in,
                              void* d_out, int out_size, void* d_ws, size_t ws_size,
                              hipStream_t stream)
{
    const float* feat = (const float*)d_in[0];
    const int*   ei   = (const int*)d_in[1];   // harness converts int64 -> int32
    const float* W    = (const float*)d_in[2];
    const float* b    = (const float*)d_in[3];
    float*       out  = (float*)d_out;

    float* a = (float*)d_ws;
    float* c = a + N_NODES;

    node_dots_kernel<<<2048, 256, 0, stream>>>(feat, W, b, a, c);

    const int nblk2 = (N_EDGES + 255) / 256;     // 2500 blocks, 1 edge/thread
    edge_kernel<<<nblk2, 256, 0, stream>>>(ei, a, c, out);
}